// Round 13
// baseline (188.702 us; speedup 1.0000x reference)
//
#include <hip/hip_runtime.h>
#include <hip/hip_bf16.h>
#include <math.h>

#define SS 160
#define DD 512
#define HH 8
#define MTOK 640
#define FFD 2048
#define NTT 257   // T+1 time-embedding rows

typedef __attribute__((ext_vector_type(8))) short bfrag8;
typedef __attribute__((ext_vector_type(4))) float facc4;
typedef unsigned short u16;

#define SWZ(row, cb) ((cb) ^ (((row)&7) << 4))

__device__ __forceinline__ void gload16(const void* g, void* l) {
  __builtin_amdgcn_global_load_lds(
      (const __attribute__((address_space(1))) void*)g,
      (__attribute__((address_space(3))) void*)l, 16, 0, 0);
}

__device__ __forceinline__ u16 f2b(float f) {
  __hip_bfloat16 hb = __float2bfloat16(f);
  return *reinterpret_cast<u16*>(&hb);
}

// ================= prep_all ================================================
__device__ void wconv_body(const float* __restrict__ src,
                           __hip_bfloat16* __restrict__ dst,
                           int K, int N, int dls, int rowoff,
                           int l, int bx, int by, float (*tile)[65])
{
  src += (size_t)l * K * N;
  dst += (size_t)l * dls + (size_t)rowoff * K;
  int k0 = by * 64, n0 = bx * 64;
  int t = threadIdx.x;
  int r = t >> 2, c0 = (t & 3) * 16;
  #pragma unroll
  for (int j = 0; j < 16; j += 4) {
    float4 v4 = *(const float4*)&src[(size_t)(k0 + r) * N + n0 + c0 + j];
    tile[r][c0 + j + 0] = v4.x; tile[r][c0 + j + 1] = v4.y;
    tile[r][c0 + j + 2] = v4.z; tile[r][c0 + j + 3] = v4.w;
  }
  __syncthreads();
  union { u16 u[8]; uint4 v; } pk;
  #pragma unroll
  for (int half = 0; half < 2; ++half) {
    #pragma unroll
    for (int j = 0; j < 8; ++j)
      pk.u[j] = f2b(tile[c0 + half * 8 + j][r]);
    *(uint4*)&dst[(size_t)(n0 + r) * K + k0 + c0 + half * 8] = pk.v;
  }
}

__global__ __launch_bounds__(256) void prep_all(
    const float* __restrict__ Wq, const float* __restrict__ Wk,
    const float* __restrict__ Wv, const float* __restrict__ Wo,
    const float* __restrict__ W1, const float* __restrict__ W2,
    const float* __restrict__ tiK,
    __hip_bfloat16* __restrict__ wqkv, __hip_bfloat16* __restrict__ wo_t,
    __hip_bfloat16* __restrict__ w1_t, __hip_bfloat16* __restrict__ w2_t,
    __hip_bfloat16* __restrict__ tikb,
    const int* __restrict__ x, const int* __restrict__ stamp,
    const float* __restrict__ tok, const float* __restrict__ month,
    const float* __restrict__ day, const float* __restrict__ g0,
    const float* __restrict__ b0, float* __restrict__ h,
    __hip_bfloat16* __restrict__ hb)
{
  __shared__ float tile[64][65];
  __shared__ float ssh[4], qsh[4];
  int idx = blockIdx.x;
  int tid = threadIdx.x;

  if (idx < 1536) {
    if (idx < 384) {
      int grp = idx / 128, r = idx % 128;
      int l = r / 64, t = r % 64;
      const float* src = grp == 0 ? Wq : (grp == 1 ? Wk : Wv);
      wconv_body(src, wqkv, 512, 512, 1536 * 512, 512 * grp, l, t % 8, t / 8, tile);
    } else if (idx < 512) {
      int r = idx - 384; int l = r / 64, t = r % 64;
      wconv_body(Wo, wo_t, 512, 512, 512 * 512, 0, l, t % 8, t / 8, tile);
    } else if (idx < 1024) {
      int r = idx - 512; int l = r / 256, t = r % 256;
      wconv_body(W1, w1_t, 512, 2048, 2048 * 512, 0, l, t % 32, t / 32, tile);
    } else {
      int r = idx - 1024; int l = r / 256, t = r % 256;
      wconv_body(W2, w2_t, 2048, 512, 512 * 2048, 0, l, t % 8, t / 8, tile);
    }
  } else if (idx < 1665) {
    int i = (idx - 1536) * 256 + tid;
    if (i < NTT * DD / 4) {
      float4 v = *(const float4*)(tiK + (size_t)i * 4);
      union { u16 u[4]; uint2 w; } pk;
      pk.u[0] = f2b(v.x); pk.u[1] = f2b(v.y);
      pk.u[2] = f2b(v.z); pk.u[3] = f2b(v.w);
      *(uint2*)(tikb + (size_t)i * 4) = pk.w;
    }
  } else {
    int m = idx - 1665;
    int b = m / SS, s = m % SS, t = tid;
    int tokid = x[m];
    float v0 = tok[tokid * DD + t];
    float v1 = tok[tokid * DD + t + 256];
    if (s > 0) {
      int sidx = (b * (SS - 1) + (s - 1)) * 3;
      int mo = stamp[sidx + 0], dy = stamp[sidx + 1];
      v0 += month[mo * DD + t]       + day[dy * DD + t];
      v1 += month[mo * DD + t + 256] + day[dy * DD + t + 256];
    }
    float sum = v0 + v1, sq = v0 * v0 + v1 * v1;
    #pragma unroll
    for (int off = 1; off < 64; off <<= 1) {
      sum += __shfl_xor(sum, off);
      sq  += __shfl_xor(sq , off);
    }
    if ((t & 63) == 0) { ssh[t >> 6] = sum; qsh[t >> 6] = sq; }
    __syncthreads();
    float fsum = ssh[0] + ssh[1] + ssh[2] + ssh[3];
    float fsq  = qsh[0] + qsh[1] + qsh[2] + qsh[3];
    float u = fsum * (1.0f / 512.0f);
    float var = fsq * (1.0f / 512.0f) - u * u;
    float r = rsqrtf(var + 1e-12f);
    float y0 = g0[t]       * ((v0 - u) * r) + b0[t];
    float y1 = g0[t + 256] * ((v1 - u) * r) + b0[t + 256];
    h[m * DD + t]        = y0;  h[m * DD + t + 256]  = y1;
    hb[m * DD + t]       = __float2bfloat16(y0);
    hb[m * DD + t + 256] = __float2bfloat16(y1);
  }
}

// ---------------- LayerNorm ----------------
__global__ __launch_bounds__(256) void ln_kernel(
    const float* __restrict__ in, const float* __restrict__ g,
    const float* __restrict__ b, float* __restrict__ out,
    __hip_bfloat16* __restrict__ outb)
{
  int m = blockIdx.x; int t = threadIdx.x;
  float v0 = in[m*DD + t];
  float v1 = in[m*DD + t + 256];
  float sum = v0+v1, sq = v0*v0+v1*v1;
  #pragma unroll
  for (int off=1; off<64; off<<=1) {
    sum += __shfl_xor(sum, off);
    sq  += __shfl_xor(sq , off);
  }
  __shared__ float ssh[4], qsh[4];
  if ((t&63)==0) { ssh[t>>6]=sum; qsh[t>>6]=sq; }
  __syncthreads();
  float fsum = ssh[0]+ssh[1]+ssh[2]+ssh[3];
  float fsq  = qsh[0]+qsh[1]+qsh[2]+qsh[3];
  float u = fsum * (1.0f/512.0f);
  float var = fsq * (1.0f/512.0f) - u*u;
  float r = rsqrtf(var + 1e-12f);
  float y0 = g[t]    *((v0-u)*r) + b[t];
  float y1 = g[t+256]*((v1-u)*r) + b[t+256];
  out[m*DD+t]     = y0;
  out[m*DD+t+256] = y1;
  if (outb) {
    outb[m*DD+t]     = __float2bfloat16(y0);
    outb[m*DD+t+256] = __float2bfloat16(y1);
  }
}

// ========== pipelined MFMA GEMM (R5-proven, KC=128 dbuf) ==========
#define EPI_RESID 1
#define EPI_GELU 2
#define EPI_QKV 3

template<int EPI, int K>
__global__ __launch_bounds__(256) void gemm_ck(
    const __hip_bfloat16* __restrict__ A,
    const __hip_bfloat16* __restrict__ Bt,
    const float* __restrict__ bias,
    const float* __restrict__ bias2,
    const float* __restrict__ bias3,
    const float* __restrict__ resid,
    float* __restrict__ Cf,
    __hip_bfloat16* __restrict__ Cb,
    int N)
{
  constexpr int KC = 128;
  constexpr int NCH = K / KC;
  __shared__ u16 As[2][64 * KC];
  __shared__ u16 Bs[2][64 * KC];
  const int tid = threadIdx.x, wv = tid >> 6, lane = tid & 63;
  const int m0 = blockIdx.y * 64, n0 = blockIdx.x * 64;
  const int wr = wv >> 1, wc = wv & 1;
  const int fr = lane & 15, fks = lane >> 4;

  const int ldsq = (wv * 4) * 1024;
  const int off0 = ldsq + lane * 16;

  #define STAGE(c, buf) do {                                                  \
    _Pragma("unroll")                                                         \
    for (int i_ = 0; i_ < 4; ++i_) {                                          \
      int ldso = ldsq + i_ * 1024;                                            \
      int off = off0 + i_ * 1024;                                             \
      int r_ = off >> 8;                                                      \
      int p_ = off & 255;                                                     \
      int ps_ = p_ ^ ((r_ & 7) << 4);                                         \
      gload16((const char*)A  + ((size_t)(m0 + r_) * K + (c) * KC) * 2 + ps_, \
              (char*)&As[buf][0] + ldso);                                     \
      gload16((const char*)Bt + ((size_t)(n0 + r_) * K + (c) * KC) * 2 + ps_, \
              (char*)&Bs[buf][0] + ldso);                                     \
    }                                                                         \
  } while (0)

  facc4 acc[2][2] = {};
  STAGE(0, 0);
  STAGE(1, 1);

  #pragma unroll
  for (int c = 0; c < NCH; ++c) {
    if (c + 1 < NCH) asm volatile("s_waitcnt vmcnt(8)\n\ts_barrier" ::: "memory");
    else             asm volatile("s_waitcnt vmcnt(0)\n\ts_barrier" ::: "memory");
    const char* ab = (const char*)&As[c & 1][0];
    const char* bb = (const char*)&Bs[c & 1][0];
    #pragma unroll
    for (int ks = 0; ks < 4; ++ks) {
      bfrag8 af[2], bfv[2];
      #pragma unroll
      for (int mf = 0; mf < 2; ++mf) {
        int rA = wr * 32 + mf * 16 + fr;
        af[mf] = *(const bfrag8*)(ab + rA * 256 + SWZ(rA, ks * 64 + fks * 16));
      }
      #pragma unroll
      for (int nf = 0; nf < 2; ++nf) {
        int rB = wc * 32 + nf * 16 + fr;
        bfv[nf] = *(const bfrag8*)(bb + rB * 256 + SWZ(rB, ks * 64 + fks * 16));
      }
      #pragma unroll
      for (int mf = 0; mf < 2; ++mf)
        #pragma unroll
        for (int nf = 0; nf < 2; ++nf)
          acc[mf][nf] = __builtin_amdgcn_mfma_f32_16x16x32_bf16(
              af[mf], bfv[nf], acc[mf][nf], 0, 0, 0);
    }
    asm volatile("s_barrier" ::: "memory");
    if (c + 2 < NCH) STAGE(c + 2, c & 1);
  }
  #undef STAGE

  #pragma unroll
  for (int mf = 0; mf < 2; ++mf) {
    #pragma unroll
    for (int nf = 0; nf < 2; ++nf) {
      int col = n0 + wc * 32 + nf * 16 + fr;
      float bb;
      if (EPI == EPI_QKV)
        bb = col < 512 ? bias[col] : (col < 1024 ? bias2[col - 512] : bias3[col - 1024]);
      else
        bb = bias[col];
      #pragma unroll
      for (int j = 0; j < 4; ++j) {
        int row = m0 + wr * 32 + mf * 16 + fks * 4 + j;
        float c = acc[mf][nf][j] + bb;
        if (EPI == EPI_RESID) {
          c += resid[(size_t)row * N + col];
          Cf[(size_t)row * N + col] = c;
        } else {
          if (EPI == EPI_GELU) c = 0.5f * c * (1.0f + erff(c * 0.70710678118654752f));
          Cb[(size_t)row * N + col] = __float2bfloat16(c);
        }
      }
    }
  }
}

// ========== fused attention: scores (MFMA) + softmax + PV (tiV in LDS) =====
__global__ __launch_bounds__(256) void attn_f(
    const __hip_bfloat16* __restrict__ qkv,
    const __hip_bfloat16* __restrict__ tikb,
    const int* __restrict__ tm, const int* __restrict__ mask,
    const float* __restrict__ tiV, __hip_bfloat16* __restrict__ hh)
{
  const int h = blockIdx.y, b = blockIdx.z;
  const int i0 = blockIdx.x * 8;
  const int tid = threadIdx.x, wv = tid >> 6, lane = tid & 63;
  const int fr = lane & 15, fks = lane >> 4;
  __shared__ __hip_bfloat16 tvs[272][64];   // 34816 B: per-head tiV slice
  __shared__ float S[8][160];
  __shared__ float Gsh[8][272];
  __shared__ float P[8][176];
  __shared__ int tmsh[8][176];

  // ---- stage tiV[., h*64..h*64+63] -> LDS bf16 (coalesced float4 reads) ----
  for (int i = tid; i < 272 * 16; i += 256) {
    int r = i >> 4, c4 = (i & 15) << 2;
    float4 v4 = {0.f, 0.f, 0.f, 0.f};
    if (r < NTT) v4 = *(const float4*)(tiV + (size_t)r * DD + h * 64 + c4);
    union { u16 u[4]; uint2 w; } pk;
    pk.u[0] = f2b(v4.x); pk.u[1] = f2b(v4.y);
    pk.u[2] = f2b(v4.z); pk.u[3] = f2b(v4.w);
    *(uint2*)&tvs[r][c4] = pk.w;
  }

  // ---- phase 1: S = q@k^T, G = q@tiK^T for this block's 8 rows ----
  bfrag8 aq0, aq1;
  {
    const __hip_bfloat16* qrow =
        qkv + (size_t)(b * SS + i0 + (fr < 8 ? fr : 7)) * 1536 + h * 64;
    aq0 = *(const bfrag8*)(qrow + fks * 8);
    aq1 = *(const bfrag8*)(qrow + 32 + fks * 8);
  }
  for (int tt = wv; tt < 27; tt += 4) {
    facc4 acc = {};
    if (tt < 10) {
      int j = tt * 16 + fr;   // < 160 always
      const __hip_bfloat16* krow = qkv + (size_t)(b * SS + j) * 1536 + 512 + h * 64;
      bfrag8 b0 = *(const bfrag8*)(krow + fks * 8);
      bfrag8 b1 = *(const bfrag8*)(krow + 32 + fks * 8);
      acc = __builtin_amdgcn_mfma_f32_16x16x32_bf16(aq0, b0, acc, 0, 0, 0);
      acc = __builtin_amdgcn_mfma_f32_16x16x32_bf16(aq1, b1, acc, 0, 0, 0);
      #pragma unroll
      for (int jj = 0; jj < 4; ++jj) {
        int qr = fks * 4 + jj;
        if (qr < 8) S[qr][tt * 16 + fr] = acc[jj];
      }
    } else {
      int t0 = (tt - 10) * 16;
      int t = min(t0 + fr, NTT - 1);   // clamp; cols >=257 never read
      const __hip_bfloat16* trow = tikb + (size_t)t * 512 + h * 64;
      bfrag8 b0 = *(const bfrag8*)(trow + fks * 8);
      bfrag8 b1 = *(const bfrag8*)(trow + 32 + fks * 8);
      acc = __builtin_amdgcn_mfma_f32_16x16x32_bf16(aq0, b0, acc, 0, 0, 0);
      acc = __builtin_amdgcn_mfma_f32_16x16x32_bf16(aq1, b1, acc, 0, 0, 0);
      #pragma unroll
      for (int jj = 0; jj < 4; ++jj) {
        int qr = fks * 4 + jj;
        if (qr < 8) Gsh[qr][t0 + fr] = acc[jj];
      }
    }
  }
  __syncthreads();

  // ---- phase 2: softmax (wave-private rows) ----
  float rinvs[2];
  #pragma unroll
  for (int rr = 0; rr < 2; ++rr) {
    const int r = wv * 2 + rr, i = i0 + r, m = b * SS + i;
    const int* tmrow = tm + (size_t)m * SS;
    float sv[3];
    float mx = -1e30f;
    #pragma unroll
    for (int g = 0; g < 3; ++g) {
      int j = lane + g * 64;
      if (j < SS) {
        int t = tmrow[j];
        tmsh[r][j] = t;
        float s = (S[r][j] + Gsh[r][t]) * 0.125f
                + 10000.0f * (1.0f - (float)mask[b * SS + j]);
        sv[g] = s; mx = fmaxf(mx, s);
      } else sv[g] = -1e30f;
    }
    #pragma unroll
    for (int off = 1; off < 64; off <<= 1) mx = fmaxf(mx, __shfl_xor(mx, off));
    float sum = 0.f;
    #pragma unroll
    for (int g = 0; g < 3; ++g) {
      int j = lane + g * 64;
      if (j < SS) { float p = expf(sv[g] - mx); P[r][j] = p; sum += p; }
    }
    #pragma unroll
    for (int off = 1; off < 64; off <<= 1) sum += __shfl_xor(sum, off);
    rinvs[rr] = 1.0f / sum;
  }

  // ---- PV: v from global (coalesced), tiV from LDS (2-way bank, free) ----
  const int r0 = wv * 2, r1 = r0 + 1;
  const int ii0 = i0 + r0, ii1 = i0 + r1;
  const __hip_bfloat16* vbase = qkv + (size_t)b * SS * 1536 + 1024 + h * 64 + lane;
  float acc0 = 0.f, acc1 = 0.f;
  #pragma unroll 4
  for (int j = 0; j < SS; ++j) {
    float vv = __bfloat162float(vbase[(size_t)j * 1536]);
    float a0 = P[r0][j], a1 = P[r1][j];
    int t0 = tmsh[r0][j], t1 = tmsh[r1][j];
    acc0 += a0 * (vv + __bfloat162float(tvs[t0][lane]));
    acc1 += a1 * (vv + __bfloat162float(tvs[t1][lane]));
  }
  hh[((size_t)(b * SS) + ii0) * DD + h * 64 + lane] = __float2bfloat16(acc0 * rinvs[0]);
  hh[((size_t)(b * SS) + ii1) * DD + h * 64 + lane] = __float2bfloat16(acc1 * rinvs[1]);
}

// ---------------- launch ----------------
extern "C" void kernel_launch(void* const* d_in, const int* in_sizes, int n_in,
                              void* d_out, int out_size, void* d_ws, size_t ws_size,
                              hipStream_t stream) {
  const int*   x     = (const int*)d_in[0];
  const int*   stamp = (const int*)d_in[1];
  const int*   mask  = (const int*)d_in[2];
  const int*   tm    = (const int*)d_in[3];
  const float* tok   = (const float*)d_in[4];
  const float* month = (const float*)d_in[5];
  const float* day   = (const float*)d_in[6];
  const float* tiK   = (const float*)d_in[7];
  const float* tiV   = (const float*)d_in[8];
  const float* g0    = (const float*)d_in[9];
  const float* b0    = (const float*)d_in[10];
  const float* Wq    = (const float*)d_in[11];
  const float* bq    = (const float*)d_in[12];
  const float* Wk    = (const float*)d_in[13];
  const float* bk    = (const float*)d_in[14];
  const float* Wv    = (const float*)d_in[15];
  const float* bv    = (const float*)d_in[16];
  const float* Wo    = (const float*)d_in[17];
  const float* bo    = (const float*)d_in[18];
  const float* g1    = (const float*)d_in[19];
  const float* b1    = (const float*)d_in[20];
  const float* W1    = (const float*)d_in[21];
  const float* c1    = (const float*)d_in[22];
  const float* W2    = (const float*)d_in[23];
  const float* c2    = (const float*)d_in[24];
  const float* g2    = (const float*)d_in[25];
  const float* b2    = (const float*)d_in[26];

  float* out = (float*)d_out;
  const size_t NT = (size_t)MTOK * DD;

  char* p = (char*)d_ws;
  float* h    = (float*)p;  p += NT * 4;
  float* tb   = (float*)p;  p += NT * 4;
  __hip_bfloat16* h_bf   = (__hip_bfloat16*)p;  p += NT * 2;
  __hip_bfloat16* hh_bf  = (__hip_bfloat16*)p;  p += NT * 2;
  __hip_bfloat16* fb_bf  = (__hip_bfloat16*)p;  p += (size_t)MTOK * FFD * 2;
  __hip_bfloat16* qkv_bf = (__hip_bfloat16*)p;  p += (size_t)MTOK * 1536 * 2;
  __hip_bfloat16* tikb   = (__hip_bfloat16*)p;  p += (size_t)NTT * DD * 2;
  __hip_bfloat16* wqkv   = (__hip_bfloat16*)p;  p += (size_t)2 * 1536 * 512 * 2;
  __hip_bfloat16* wo_t   = (__hip_bfloat16*)p;  p += (size_t)2 * 512 * 512 * 2;
  __hip_bfloat16* w1_t   = (__hip_bfloat16*)p;  p += (size_t)2 * 2048 * 512 * 2;
  __hip_bfloat16* w2_t   = (__hip_bfloat16*)p;  p += (size_t)2 * 512 * 2048 * 2;

  prep_all<<<2305, 256, 0, stream>>>(Wq, Wk, Wv, Wo, W1, W2, tiK,
                                     wqkv, wo_t, w1_t, w2_t, tikb,
                                     x, stamp, tok, month, day, g0, b0, h, h_bf);

  // gemm_ck arg order: A, Bt, bias, bias2, bias3, resid, Cf, Cb, N  (9 args)
  for (int l = 0; l < 2; ++l) {
    gemm_ck<EPI_QKV, 512><<<dim3(24, 10), 256, 0, stream>>>(
        h_bf, wqkv + (size_t)l * 1536 * 512, bq + l*DD, bk + l*DD, bv + l*DD,
        nullptr, nullptr, qkv_bf, 1536);

    attn_f<<<dim3(20, 8, 4), 256, 0, stream>>>(qkv_bf, tikb, tm, mask, tiV, hh_bf);

    gemm_ck<EPI_RESID, 512><<<dim3(8, 10), 256, 0, stream>>>(
        hh_bf, wo_t + (size_t)l * 512 * 512, bo + l*DD, nullptr, nullptr,
        h, tb, nullptr, 512);
    ln_kernel<<<MTOK, 256, 0, stream>>>(tb, g1 + l*DD, b1 + l*DD, h, h_bf);

    gemm_ck<EPI_GELU, 512><<<dim3(32, 10), 256, 0, stream>>>(
        h_bf, w1_t + (size_t)l * 2048 * 512, c1 + l*FFD, nullptr, nullptr,
        nullptr, nullptr, fb_bf, 2048);

    gemm_ck<EPI_RESID, 2048><<<dim3(8, 10), 256, 0, stream>>>(
        fb_bf, w2_t + (size_t)l * 512 * 2048, c2 + l*DD, nullptr, nullptr,
        h, tb, nullptr, 512);
    ln_kernel<<<MTOK, 256, 0, stream>>>(tb, g2 + l*DD, b2 + l*DD,
                                        (l == 1) ? out : h,
                                        (l == 1) ? nullptr : h_bf);
  }
}

// Round 14
// 128.733 us; speedup vs baseline: 1.4658x; 1.4658x over previous
//
#include <hip/hip_runtime.h>
#include <hip/hip_bf16.h>
#include <math.h>

#define SS 160
#define DD 512
#define HH 8
#define MTOK 640
#define FFD 2048
#define NTT 257   // T+1 time-embedding rows
#define NTE (MTOK * DD)

typedef __attribute__((ext_vector_type(8))) short bfrag8;
typedef __attribute__((ext_vector_type(4))) float facc4;
typedef unsigned short u16;

#define SWZ(row, cb) ((cb) ^ (((row)&7) << 4))

__device__ __forceinline__ void gload16(const void* g, void* l) {
  __builtin_amdgcn_global_load_lds(
      (const __attribute__((address_space(1))) void*)g,
      (__attribute__((address_space(3))) void*)l, 16, 0, 0);
}

__device__ __forceinline__ u16 f2b(float f) {
  __hip_bfloat16 hb = __float2bfloat16(f);
  return *reinterpret_cast<u16*>(&hb);
}

// ================= prep_all ================================================
__device__ void wconv_body(const float* __restrict__ src,
                           __hip_bfloat16* __restrict__ dst,
                           int K, int N, int dls, int rowoff,
                           int l, int bx, int by, float (*tile)[65])
{
  src += (size_t)l * K * N;
  dst += (size_t)l * dls + (size_t)rowoff * K;
  int k0 = by * 64, n0 = bx * 64;
  int t = threadIdx.x;
  int r = t >> 2, c0 = (t & 3) * 16;
  #pragma unroll
  for (int j = 0; j < 16; j += 4) {
    float4 v4 = *(const float4*)&src[(size_t)(k0 + r) * N + n0 + c0 + j];
    tile[r][c0 + j + 0] = v4.x; tile[r][c0 + j + 1] = v4.y;
    tile[r][c0 + j + 2] = v4.z; tile[r][c0 + j + 3] = v4.w;
  }
  __syncthreads();
  union { u16 u[8]; uint4 v; } pk;
  #pragma unroll
  for (int half = 0; half < 2; ++half) {
    #pragma unroll
    for (int j = 0; j < 8; ++j)
      pk.u[j] = f2b(tile[c0 + half * 8 + j][r]);
    *(uint4*)&dst[(size_t)(n0 + r) * K + k0 + c0 + half * 8] = pk.v;
  }
}

__global__ __launch_bounds__(256) void prep_all(
    const float* __restrict__ Wq, const float* __restrict__ Wk,
    const float* __restrict__ Wv, const float* __restrict__ Wo,
    const float* __restrict__ W1, const float* __restrict__ W2,
    const float* __restrict__ tiK,
    __hip_bfloat16* __restrict__ wqkv, __hip_bfloat16* __restrict__ wo_t,
    __hip_bfloat16* __restrict__ w1_t, __hip_bfloat16* __restrict__ w2_t,
    __hip_bfloat16* __restrict__ tikb,
    const int* __restrict__ x, const int* __restrict__ stamp,
    const float* __restrict__ tok, const float* __restrict__ month,
    const float* __restrict__ day, const float* __restrict__ g0,
    const float* __restrict__ b0, float* __restrict__ h,
    __hip_bfloat16* __restrict__ hb)
{
  __shared__ float tile[64][65];
  __shared__ float ssh[4], qsh[4];
  int idx = blockIdx.x;
  int tid = threadIdx.x;

  if (idx < 1536) {
    if (idx < 384) {
      int grp = idx / 128, r = idx % 128;
      int l = r / 64, t = r % 64;
      const float* src = grp == 0 ? Wq : (grp == 1 ? Wk : Wv);
      wconv_body(src, wqkv, 512, 512, 1536 * 512, 512 * grp, l, t % 8, t / 8, tile);
    } else if (idx < 512) {
      int r = idx - 384; int l = r / 64, t = r % 64;
      wconv_body(Wo, wo_t, 512, 512, 512 * 512, 0, l, t % 8, t / 8, tile);
    } else if (idx < 1024) {
      int r = idx - 512; int l = r / 256, t = r % 256;
      wconv_body(W1, w1_t, 512, 2048, 2048 * 512, 0, l, t % 32, t / 32, tile);
    } else {
      int r = idx - 1024; int l = r / 256, t = r % 256;
      wconv_body(W2, w2_t, 2048, 512, 512 * 2048, 0, l, t % 8, t / 8, tile);
    }
  } else if (idx < 1665) {
    int i = (idx - 1536) * 256 + tid;
    if (i < NTT * DD / 4) {
      float4 v = *(const float4*)(tiK + (size_t)i * 4);
      union { u16 u[4]; uint2 w; } pk;
      pk.u[0] = f2b(v.x); pk.u[1] = f2b(v.y);
      pk.u[2] = f2b(v.z); pk.u[3] = f2b(v.w);
      *(uint2*)(tikb + (size_t)i * 4) = pk.w;
    }
  } else {
    int m = idx - 1665;
    int b = m / SS, s = m % SS, t = tid;
    int tokid = x[m];
    float v0 = tok[tokid * DD + t];
    float v1 = tok[tokid * DD + t + 256];
    if (s > 0) {
      int sidx = (b * (SS - 1) + (s - 1)) * 3;
      int mo = stamp[sidx + 0], dy = stamp[sidx + 1];
      v0 += month[mo * DD + t]       + day[dy * DD + t];
      v1 += month[mo * DD + t + 256] + day[dy * DD + t + 256];
    }
    float sum = v0 + v1, sq = v0 * v0 + v1 * v1;
    #pragma unroll
    for (int off = 1; off < 64; off <<= 1) {
      sum += __shfl_xor(sum, off);
      sq  += __shfl_xor(sq , off);
    }
    if ((t & 63) == 0) { ssh[t >> 6] = sum; qsh[t >> 6] = sq; }
    __syncthreads();
    float fsum = ssh[0] + ssh[1] + ssh[2] + ssh[3];
    float fsq  = qsh[0] + qsh[1] + qsh[2] + qsh[3];
    float u = fsum * (1.0f / 512.0f);
    float var = fsq * (1.0f / 512.0f) - u * u;
    float r = rsqrtf(var + 1e-12f);
    float y0 = g0[t]       * ((v0 - u) * r) + b0[t];
    float y1 = g0[t + 256] * ((v1 - u) * r) + b0[t + 256];
    h[m * DD + t]        = y0;  h[m * DD + t + 256]  = y1;
    hb[m * DD + t]       = __float2bfloat16(y0);
    hb[m * DD + t + 256] = __float2bfloat16(y1);
  }
}

// ---------------- ln_red: LN( sum(4 partials) + bias + resid ) ------------
__global__ __launch_bounds__(256) void ln_red(
    const float* __restrict__ parts,   // [4][MTOK][512]
    const float* __restrict__ resid,   // [MTOK][512]
    const float* __restrict__ bias,    // [512]
    const float* __restrict__ g, const float* __restrict__ b,
    float* __restrict__ out, __hip_bfloat16* __restrict__ outb)
{
  int m = blockIdx.x; int t = threadIdx.x;
  float v0 = bias[t]       + resid[(size_t)m * DD + t];
  float v1 = bias[t + 256] + resid[(size_t)m * DD + t + 256];
  #pragma unroll
  for (int s = 0; s < 4; ++s) {
    v0 += parts[(size_t)s * NTE + (size_t)m * DD + t];
    v1 += parts[(size_t)s * NTE + (size_t)m * DD + t + 256];
  }
  float sum = v0 + v1, sq = v0 * v0 + v1 * v1;
  #pragma unroll
  for (int off = 1; off < 64; off <<= 1) {
    sum += __shfl_xor(sum, off);
    sq  += __shfl_xor(sq , off);
  }
  __shared__ float ssh[4], qsh[4];
  if ((t & 63) == 0) { ssh[t >> 6] = sum; qsh[t >> 6] = sq; }
  __syncthreads();
  float fsum = ssh[0] + ssh[1] + ssh[2] + ssh[3];
  float fsq  = qsh[0] + qsh[1] + qsh[2] + qsh[3];
  float u = fsum * (1.0f / 512.0f);
  float var = fsq * (1.0f / 512.0f) - u * u;
  float r = rsqrtf(var + 1e-12f);
  float y0 = g[t]       * ((v0 - u) * r) + b[t];
  float y1 = g[t + 256] * ((v1 - u) * r) + b[t + 256];
  out[(size_t)m * DD + t]       = y0;
  out[(size_t)m * DD + t + 256] = y1;
  if (outb) {
    outb[(size_t)m * DD + t]       = __float2bfloat16(y0);
    outb[(size_t)m * DD + t + 256] = __float2bfloat16(y1);
  }
}

// ========== pipelined MFMA GEMM, split-K capable ==========
// KEXT = K-extent this block covers; KSTRIDE = row stride of A/Bt.
// blockIdx.z = K-slice index (A/Bt offset kz*KEXT; EPI_PART writes partial
// to Cf + kz*pstride).
#define EPI_RESID 1
#define EPI_GELU 2
#define EPI_QKV 3
#define EPI_PART 4

template<int EPI, int KEXT, int KSTRIDE>
__global__ __launch_bounds__(256) void gemm_ck(
    const __hip_bfloat16* __restrict__ A,
    const __hip_bfloat16* __restrict__ Bt,
    const float* __restrict__ bias,
    const float* __restrict__ bias2,
    const float* __restrict__ bias3,
    const float* __restrict__ resid,
    float* __restrict__ Cf,
    __hip_bfloat16* __restrict__ Cb,
    int N, int pstride)
{
  constexpr int KC = 128;
  constexpr int NCH = KEXT / KC;
  __shared__ u16 As[2][64 * KC];
  __shared__ u16 Bs[2][64 * KC];
  const int tid = threadIdx.x, wv = tid >> 6, lane = tid & 63;
  const int m0 = blockIdx.y * 64, n0 = blockIdx.x * 64;
  const int kz = blockIdx.z;
  const int wr = wv >> 1, wc = wv & 1;
  const int fr = lane & 15, fks = lane >> 4;

  A  += (size_t)kz * KEXT;
  Bt += (size_t)kz * KEXT;

  const int ldsq = (wv * 4) * 1024;
  const int off0 = ldsq + lane * 16;

  #define STAGE(c, buf) do {                                                  \
    _Pragma("unroll")                                                         \
    for (int i_ = 0; i_ < 4; ++i_) {                                          \
      int ldso = ldsq + i_ * 1024;                                            \
      int off = off0 + i_ * 1024;                                             \
      int r_ = off >> 8;                                                      \
      int p_ = off & 255;                                                     \
      int ps_ = p_ ^ ((r_ & 7) << 4);                                         \
      gload16((const char*)A  + ((size_t)(m0 + r_) * KSTRIDE + (c) * KC) * 2 + ps_, \
              (char*)&As[buf][0] + ldso);                                     \
      gload16((const char*)Bt + ((size_t)(n0 + r_) * KSTRIDE + (c) * KC) * 2 + ps_, \
              (char*)&Bs[buf][0] + ldso);                                     \
    }                                                                         \
  } while (0)

  facc4 acc[2][2] = {};
  STAGE(0, 0);
  if (NCH > 1) STAGE(1, 1);

  #pragma unroll
  for (int c = 0; c < NCH; ++c) {
    if (c + 1 < NCH) asm volatile("s_waitcnt vmcnt(8)\n\ts_barrier" ::: "memory");
    else             asm volatile("s_waitcnt vmcnt(0)\n\ts_barrier" ::: "memory");
    const char* ab = (const char*)&As[c & 1][0];
    const char* bb = (const char*)&Bs[c & 1][0];
    #pragma unroll
    for (int ks = 0; ks < 4; ++ks) {
      bfrag8 af[2], bfv[2];
      #pragma unroll
      for (int mf = 0; mf < 2; ++mf) {
        int rA = wr * 32 + mf * 16 + fr;
        af[mf] = *(const bfrag8*)(ab + rA * 256 + SWZ(rA, ks * 64 + fks * 16));
      }
      #pragma unroll
      for (int nf = 0; nf < 2; ++nf) {
        int rB = wc * 32 + nf * 16 + fr;
        bfv[nf] = *(const bfrag8*)(bb + rB * 256 + SWZ(rB, ks * 64 + fks * 16));
      }
      #pragma unroll
      for (int mf = 0; mf < 2; ++mf)
        #pragma unroll
        for (int nf = 0; nf < 2; ++nf)
          acc[mf][nf] = __builtin_amdgcn_mfma_f32_16x16x32_bf16(
              af[mf], bfv[nf], acc[mf][nf], 0, 0, 0);
    }
    asm volatile("s_barrier" ::: "memory");
    if (c + 2 < NCH) STAGE(c + 2, c & 1);
  }
  #undef STAGE

  #pragma unroll
  for (int mf = 0; mf < 2; ++mf) {
    #pragma unroll
    for (int nf = 0; nf < 2; ++nf) {
      int col = n0 + wc * 32 + nf * 16 + fr;
      float bb2 = 0.f;
      if (EPI == EPI_QKV)
        bb2 = col < 512 ? bias[col] : (col < 1024 ? bias2[col - 512] : bias3[col - 1024]);
      else if (EPI != EPI_PART)
        bb2 = bias[col];
      #pragma unroll
      for (int j = 0; j < 4; ++j) {
        int row = m0 + wr * 32 + mf * 16 + fks * 4 + j;
        float c = acc[mf][nf][j] + bb2;
        if (EPI == EPI_PART) {
          Cf[(size_t)kz * pstride + (size_t)row * N + col] = c;
        } else if (EPI == EPI_RESID) {
          c += resid[(size_t)row * N + col];
          Cf[(size_t)row * N + col] = c;
        } else {
          if (EPI == EPI_GELU) c = 0.5f * c * (1.0f + erff(c * 0.70710678118654752f));
          Cb[(size_t)row * N + col] = __float2bfloat16(c);
        }
      }
    }
  }
}

// ========== fused attention (R12-proven): scores MFMA + softmax + PV =======
__global__ __launch_bounds__(256) void attn_f(
    const __hip_bfloat16* __restrict__ qkv,
    const __hip_bfloat16* __restrict__ tikb,
    const int* __restrict__ tm, const int* __restrict__ mask,
    const float* __restrict__ tiV, __hip_bfloat16* __restrict__ hh)
{
  const int h = blockIdx.y, b = blockIdx.z;
  const int i0 = blockIdx.x * 8;
  const int tid = threadIdx.x, wv = tid >> 6, lane = tid & 63;
  const int fr = lane & 15, fks = lane >> 4;
  __shared__ float S[8][160];
  __shared__ float Gsh[8][272];
  __shared__ float P[8][176];
  __shared__ int tmsh[8][176];

  bfrag8 aq0, aq1;
  {
    const __hip_bfloat16* qrow =
        qkv + (size_t)(b * SS + i0 + (fr < 8 ? fr : 7)) * 1536 + h * 64;
    aq0 = *(const bfrag8*)(qrow + fks * 8);
    aq1 = *(const bfrag8*)(qrow + 32 + fks * 8);
  }
  for (int tt = wv; tt < 27; tt += 4) {
    facc4 acc = {};
    if (tt < 10) {
      int j = tt * 16 + fr;
      const __hip_bfloat16* krow = qkv + (size_t)(b * SS + j) * 1536 + 512 + h * 64;
      bfrag8 b0 = *(const bfrag8*)(krow + fks * 8);
      bfrag8 b1 = *(const bfrag8*)(krow + 32 + fks * 8);
      acc = __builtin_amdgcn_mfma_f32_16x16x32_bf16(aq0, b0, acc, 0, 0, 0);
      acc = __builtin_amdgcn_mfma_f32_16x16x32_bf16(aq1, b1, acc, 0, 0, 0);
      #pragma unroll
      for (int jj = 0; jj < 4; ++jj) {
        int qr = fks * 4 + jj;
        if (qr < 8) S[qr][tt * 16 + fr] = acc[jj];
      }
    } else {
      int t0 = (tt - 10) * 16;
      int t = min(t0 + fr, NTT - 1);
      const __hip_bfloat16* trow = tikb + (size_t)t * 512 + h * 64;
      bfrag8 b0 = *(const bfrag8*)(trow + fks * 8);
      bfrag8 b1 = *(const bfrag8*)(trow + 32 + fks * 8);
      acc = __builtin_amdgcn_mfma_f32_16x16x32_bf16(aq0, b0, acc, 0, 0, 0);
      acc = __builtin_amdgcn_mfma_f32_16x16x32_bf16(aq1, b1, acc, 0, 0, 0);
      #pragma unroll
      for (int jj = 0; jj < 4; ++jj) {
        int qr = fks * 4 + jj;
        if (qr < 8) Gsh[qr][t0 + fr] = acc[jj];
      }
    }
  }
  __syncthreads();

  float rinvs[2];
  #pragma unroll
  for (int rr = 0; rr < 2; ++rr) {
    const int r = wv * 2 + rr, i = i0 + r, m = b * SS + i;
    const int* tmrow = tm + (size_t)m * SS;
    float sv[3];
    float mx = -1e30f;
    #pragma unroll
    for (int g = 0; g < 3; ++g) {
      int j = lane + g * 64;
      if (j < SS) {
        int t = tmrow[j];
        tmsh[r][j] = t;
        float s = (S[r][j] + Gsh[r][t]) * 0.125f
                + 10000.0f * (1.0f - (float)mask[b * SS + j]);
        sv[g] = s; mx = fmaxf(mx, s);
      } else sv[g] = -1e30f;
    }
    #pragma unroll
    for (int off = 1; off < 64; off <<= 1) mx = fmaxf(mx, __shfl_xor(mx, off));
    float sum = 0.f;
    #pragma unroll
    for (int g = 0; g < 3; ++g) {
      int j = lane + g * 64;
      if (j < SS) { float p = expf(sv[g] - mx); P[r][j] = p; sum += p; }
    }
    #pragma unroll
    for (int off = 1; off < 64; off <<= 1) sum += __shfl_xor(sum, off);
    rinvs[rr] = 1.0f / sum;
  }

  const int r0 = wv * 2, r1 = r0 + 1;
  const int ii0 = i0 + r0, ii1 = i0 + r1;
  const __hip_bfloat16* vbase = qkv + (size_t)b * SS * 1536 + 1024 + h * 64 + lane;
  const float* tvbase = tiV + h * 64 + lane;
  float acc0 = 0.f, acc1 = 0.f;
  #pragma unroll 4
  for (int j = 0; j < SS; ++j) {
    float vv = __bfloat162float(vbase[(size_t)j * 1536]);
    float a0 = P[r0][j], a1 = P[r1][j];
    int t0 = tmsh[r0][j], t1 = tmsh[r1][j];
    acc0 += a0 * (vv + tvbase[(size_t)t0 * 512]);
    acc1 += a1 * (vv + tvbase[(size_t)t1 * 512]);
  }
  hh[((size_t)(b * SS) + ii0) * DD + h * 64 + lane] = __float2bfloat16(acc0 * rinvs[0]);
  hh[((size_t)(b * SS) + ii1) * DD + h * 64 + lane] = __float2bfloat16(acc1 * rinvs[1]);
}

// ---------------- launch ----------------
extern "C" void kernel_launch(void* const* d_in, const int* in_sizes, int n_in,
                              void* d_out, int out_size, void* d_ws, size_t ws_size,
                              hipStream_t stream) {
  const int*   x     = (const int*)d_in[0];
  const int*   stamp = (const int*)d_in[1];
  const int*   mask  = (const int*)d_in[2];
  const int*   tm    = (const int*)d_in[3];
  const float* tok   = (const float*)d_in[4];
  const float* month = (const float*)d_in[5];
  const float* day   = (const float*)d_in[6];
  const float* tiK   = (const float*)d_in[7];
  const float* tiV   = (const float*)d_in[8];
  const float* g0    = (const float*)d_in[9];
  const float* b0    = (const float*)d_in[10];
  const float* Wq    = (const float*)d_in[11];
  const float* bq    = (const float*)d_in[12];
  const float* Wk    = (const float*)d_in[13];
  const float* bk    = (const float*)d_in[14];
  const float* Wv    = (const float*)d_in[15];
  const float* bv    = (const float*)d_in[16];
  const float* Wo    = (const float*)d_in[17];
  const float* bo    = (const float*)d_in[18];
  const float* g1    = (const float*)d_in[19];
  const float* b1    = (const float*)d_in[20];
  const float* W1    = (const float*)d_in[21];
  const float* c1    = (const float*)d_in[22];
  const float* W2    = (const float*)d_in[23];
  const float* c2    = (const float*)d_in[24];
  const float* g2    = (const float*)d_in[25];
  const float* b2    = (const float*)d_in[26];

  float* out = (float*)d_out;
  const size_t NT = (size_t)MTOK * DD;

  char* p = (char*)d_ws;
  float* h    = (float*)p;  p += NT * 4;
  float* tbp  = (float*)p;  p += (size_t)4 * NT * 4;   // 4 K-slice partials
  __hip_bfloat16* h_bf   = (__hip_bfloat16*)p;  p += NT * 2;
  __hip_bfloat16* hh_bf  = (__hip_bfloat16*)p;  p += NT * 2;
  __hip_bfloat16* fb_bf  = (__hip_bfloat16*)p;  p += (size_t)MTOK * FFD * 2;
  __hip_bfloat16* qkv_bf = (__hip_bfloat16*)p;  p += (size_t)MTOK * 1536 * 2;
  __hip_bfloat16* tikb   = (__hip_bfloat16*)p;  p += (size_t)NTT * DD * 2;
  __hip_bfloat16* wqkv   = (__hip_bfloat16*)p;  p += (size_t)2 * 1536 * 512 * 2;
  __hip_bfloat16* wo_t   = (__hip_bfloat16*)p;  p += (size_t)2 * 512 * 512 * 2;
  __hip_bfloat16* w1_t   = (__hip_bfloat16*)p;  p += (size_t)2 * 2048 * 512 * 2;
  __hip_bfloat16* w2_t   = (__hip_bfloat16*)p;  p += (size_t)2 * 512 * 2048 * 2;

  prep_all<<<2305, 256, 0, stream>>>(Wq, Wk, Wv, Wo, W1, W2, tiK,
                                     wqkv, wo_t, w1_t, w2_t, tikb,
                                     x, stamp, tok, month, day, g0, b0, h, h_bf);

  // gemm_ck args (10): A, Bt, bias, bias2, bias3, resid, Cf, Cb, N, pstride
  for (int l = 0; l < 2; ++l) {
    gemm_ck<EPI_QKV, 512, 512><<<dim3(24, 10), 256, 0, stream>>>(
        h_bf, wqkv + (size_t)l * 1536 * 512, bq + l*DD, bk + l*DD, bv + l*DD,
        nullptr, nullptr, qkv_bf, 1536, 0);

    attn_f<<<dim3(20, 8, 4), 256, 0, stream>>>(qkv_bf, tikb, tm, mask, tiV, hh_bf);

    // WO split-K: 4 slices of 128; partials -> tbp
    gemm_ck<EPI_PART, 128, 512><<<dim3(8, 10, 4), 256, 0, stream>>>(
        hh_bf, wo_t + (size_t)l * 512 * 512, nullptr, nullptr, nullptr,
        nullptr, tbp, nullptr, 512, (int)NT);
    ln_red<<<MTOK, 256, 0, stream>>>(tbp, h, bo + l*DD,
                                     g1 + l*DD, b1 + l*DD, h, h_bf);

    gemm_ck<EPI_GELU, 512, 512><<<dim3(32, 10), 256, 0, stream>>>(
        h_bf, w1_t + (size_t)l * 2048 * 512, c1 + l*FFD, nullptr, nullptr,
        nullptr, nullptr, fb_bf, 2048, 0);

    // FF2 split-K: 4 slices of 512; partials -> tbp
    gemm_ck<EPI_PART, 512, 2048><<<dim3(8, 10, 4), 256, 0, stream>>>(
        fb_bf, w2_t + (size_t)l * 512 * 2048, nullptr, nullptr, nullptr,
        nullptr, tbp, nullptr, 512, (int)NT);
    ln_red<<<MTOK, 256, 0, stream>>>(tbp, h, c2 + l*DD,
                                     g2 + l*DD, b2 + l*DD,
                                     (l == 1) ? out : h,
                                     (l == 1) ? nullptr : h_bf);
  }
}

// Round 15
// 122.426 us; speedup vs baseline: 1.5414x; 1.0515x over previous
//
#include <hip/hip_runtime.h>
#include <hip/hip_bf16.h>
#include <math.h>

#define SS 160
#define DD 512
#define HH 8
#define MTOK 640
#define FFD 2048
#define NTT 257   // T+1 time-embedding rows
#define NTE (MTOK * DD)

typedef __attribute__((ext_vector_type(8))) short bfrag8;
typedef __attribute__((ext_vector_type(4))) float facc4;
typedef unsigned short u16;

#define SWZ(row, cb) ((cb) ^ (((row)&7) << 4))

__device__ __forceinline__ void gload16(const void* g, void* l) {
  __builtin_amdgcn_global_load_lds(
      (const __attribute__((address_space(1))) void*)g,
      (__attribute__((address_space(3))) void*)l, 16, 0, 0);
}

__device__ __forceinline__ u16 f2b(float f) {
  __hip_bfloat16 hb = __float2bfloat16(f);
  return *reinterpret_cast<u16*>(&hb);
}

// ================= prep_all ================================================
__device__ void wconv_body(const float* __restrict__ src,
                           __hip_bfloat16* __restrict__ dst,
                           int K, int N, int dls, int rowoff,
                           int l, int bx, int by, float (*tile)[65])
{
  src += (size_t)l * K * N;
  dst += (size_t)l * dls + (size_t)rowoff * K;
  int k0 = by * 64, n0 = bx * 64;
  int t = threadIdx.x;
  int r = t >> 2, c0 = (t & 3) * 16;
  #pragma unroll
  for (int j = 0; j < 16; j += 4) {
    float4 v4 = *(const float4*)&src[(size_t)(k0 + r) * N + n0 + c0 + j];
    tile[r][c0 + j + 0] = v4.x; tile[r][c0 + j + 1] = v4.y;
    tile[r][c0 + j + 2] = v4.z; tile[r][c0 + j + 3] = v4.w;
  }
  __syncthreads();
  union { u16 u[8]; uint4 v; } pk;
  #pragma unroll
  for (int half = 0; half < 2; ++half) {
    #pragma unroll
    for (int j = 0; j < 8; ++j)
      pk.u[j] = f2b(tile[c0 + half * 8 + j][r]);
    *(uint4*)&dst[(size_t)(n0 + r) * K + k0 + c0 + half * 8] = pk.v;
  }
}

__global__ __launch_bounds__(256) void prep_all(
    const float* __restrict__ Wq, const float* __restrict__ Wk,
    const float* __restrict__ Wv, const float* __restrict__ Wo,
    const float* __restrict__ W1, const float* __restrict__ W2,
    const float* __restrict__ tiK,
    __hip_bfloat16* __restrict__ wqkv, __hip_bfloat16* __restrict__ wo_t,
    __hip_bfloat16* __restrict__ w1_t, __hip_bfloat16* __restrict__ w2_t,
    __hip_bfloat16* __restrict__ tikb,
    const int* __restrict__ x, const int* __restrict__ stamp,
    const float* __restrict__ tok, const float* __restrict__ month,
    const float* __restrict__ day, const float* __restrict__ g0,
    const float* __restrict__ b0, float* __restrict__ h,
    __hip_bfloat16* __restrict__ hb)
{
  __shared__ float tile[64][65];
  __shared__ float ssh[4], qsh[4];
  int idx = blockIdx.x;
  int tid = threadIdx.x;

  if (idx < 1536) {
    if (idx < 384) {
      int grp = idx / 128, r = idx % 128;
      int l = r / 64, t = r % 64;
      const float* src = grp == 0 ? Wq : (grp == 1 ? Wk : Wv);
      wconv_body(src, wqkv, 512, 512, 1536 * 512, 512 * grp, l, t % 8, t / 8, tile);
    } else if (idx < 512) {
      int r = idx - 384; int l = r / 64, t = r % 64;
      wconv_body(Wo, wo_t, 512, 512, 512 * 512, 0, l, t % 8, t / 8, tile);
    } else if (idx < 1024) {
      int r = idx - 512; int l = r / 256, t = r % 256;
      wconv_body(W1, w1_t, 512, 2048, 2048 * 512, 0, l, t % 32, t / 32, tile);
    } else {
      int r = idx - 1024; int l = r / 256, t = r % 256;
      wconv_body(W2, w2_t, 2048, 512, 512 * 2048, 0, l, t % 8, t / 8, tile);
    }
  } else if (idx < 1665) {
    int i = (idx - 1536) * 256 + tid;
    if (i < NTT * DD / 4) {
      float4 v = *(const float4*)(tiK + (size_t)i * 4);
      union { u16 u[4]; uint2 w; } pk;
      pk.u[0] = f2b(v.x); pk.u[1] = f2b(v.y);
      pk.u[2] = f2b(v.z); pk.u[3] = f2b(v.w);
      *(uint2*)(tikb + (size_t)i * 4) = pk.w;
    }
  } else {
    int m = idx - 1665;
    int b = m / SS, s = m % SS, t = tid;
    int tokid = x[m];
    float v0 = tok[tokid * DD + t];
    float v1 = tok[tokid * DD + t + 256];
    if (s > 0) {
      int sidx = (b * (SS - 1) + (s - 1)) * 3;
      int mo = stamp[sidx + 0], dy = stamp[sidx + 1];
      v0 += month[mo * DD + t]       + day[dy * DD + t];
      v1 += month[mo * DD + t + 256] + day[dy * DD + t + 256];
    }
    float sum = v0 + v1, sq = v0 * v0 + v1 * v1;
    #pragma unroll
    for (int off = 1; off < 64; off <<= 1) {
      sum += __shfl_xor(sum, off);
      sq  += __shfl_xor(sq , off);
    }
    if ((t & 63) == 0) { ssh[t >> 6] = sum; qsh[t >> 6] = sq; }
    __syncthreads();
    float fsum = ssh[0] + ssh[1] + ssh[2] + ssh[3];
    float fsq  = qsh[0] + qsh[1] + qsh[2] + qsh[3];
    float u = fsum * (1.0f / 512.0f);
    float var = fsq * (1.0f / 512.0f) - u * u;
    float r = rsqrtf(var + 1e-12f);
    float y0 = g0[t]       * ((v0 - u) * r) + b0[t];
    float y1 = g0[t + 256] * ((v1 - u) * r) + b0[t + 256];
    h[m * DD + t]        = y0;  h[m * DD + t + 256]  = y1;
    hb[m * DD + t]       = __float2bfloat16(y0);
    hb[m * DD + t + 256] = __float2bfloat16(y1);
  }
}

// ---------------- ln_red: LN( sum(4 partials) + bias + resid ) ------------
__global__ __launch_bounds__(256) void ln_red(
    const float* __restrict__ parts,   // [4][MTOK][512]
    const float* __restrict__ resid,   // [MTOK][512]
    const float* __restrict__ bias,    // [512]
    const float* __restrict__ g, const float* __restrict__ b,
    float* __restrict__ out, __hip_bfloat16* __restrict__ outb)
{
  int m = blockIdx.x; int t = threadIdx.x;
  float v0 = bias[t]       + resid[(size_t)m * DD + t];
  float v1 = bias[t + 256] + resid[(size_t)m * DD + t + 256];
  #pragma unroll
  for (int s = 0; s < 4; ++s) {
    v0 += parts[(size_t)s * NTE + (size_t)m * DD + t];
    v1 += parts[(size_t)s * NTE + (size_t)m * DD + t + 256];
  }
  float sum = v0 + v1, sq = v0 * v0 + v1 * v1;
  #pragma unroll
  for (int off = 1; off < 64; off <<= 1) {
    sum += __shfl_xor(sum, off);
    sq  += __shfl_xor(sq , off);
  }
  __shared__ float ssh[4], qsh[4];
  if ((t & 63) == 0) { ssh[t >> 6] = sum; qsh[t >> 6] = sq; }
  __syncthreads();
  float fsum = ssh[0] + ssh[1] + ssh[2] + ssh[3];
  float fsq  = qsh[0] + qsh[1] + qsh[2] + qsh[3];
  float u = fsum * (1.0f / 512.0f);
  float var = fsq * (1.0f / 512.0f) - u * u;
  float r = rsqrtf(var + 1e-12f);
  float y0 = g[t]       * ((v0 - u) * r) + b[t];
  float y1 = g[t + 256] * ((v1 - u) * r) + b[t + 256];
  out[(size_t)m * DD + t]       = y0;
  out[(size_t)m * DD + t + 256] = y1;
  if (outb) {
    outb[(size_t)m * DD + t]       = __float2bfloat16(y0);
    outb[(size_t)m * DD + t + 256] = __float2bfloat16(y1);
  }
}

// ========== pipelined MFMA GEMM, split-K capable ==========
#define EPI_RESID 1
#define EPI_GELU 2
#define EPI_QKV 3
#define EPI_PART 4

template<int EPI, int KEXT, int KSTRIDE>
__global__ __launch_bounds__(256) void gemm_ck(
    const __hip_bfloat16* __restrict__ A,
    const __hip_bfloat16* __restrict__ Bt,
    const float* __restrict__ bias,
    const float* __restrict__ bias2,
    const float* __restrict__ bias3,
    const float* __restrict__ resid,
    float* __restrict__ Cf,
    __hip_bfloat16* __restrict__ Cb,
    int N, int pstride)
{
  constexpr int KC = 128;
  constexpr int NCH = KEXT / KC;
  __shared__ u16 As[2][64 * KC];
  __shared__ u16 Bs[2][64 * KC];
  const int tid = threadIdx.x, wv = tid >> 6, lane = tid & 63;
  const int m0 = blockIdx.y * 64, n0 = blockIdx.x * 64;
  const int kz = blockIdx.z;
  const int wr = wv >> 1, wc = wv & 1;
  const int fr = lane & 15, fks = lane >> 4;

  A  += (size_t)kz * KEXT;
  Bt += (size_t)kz * KEXT;

  const int ldsq = (wv * 4) * 1024;
  const int off0 = ldsq + lane * 16;

  #define STAGE(c, buf) do {                                                  \
    _Pragma("unroll")                                                         \
    for (int i_ = 0; i_ < 4; ++i_) {                                          \
      int ldso = ldsq + i_ * 1024;                                            \
      int off = off0 + i_ * 1024;                                             \
      int r_ = off >> 8;                                                      \
      int p_ = off & 255;                                                     \
      int ps_ = p_ ^ ((r_ & 7) << 4);                                         \
      gload16((const char*)A  + ((size_t)(m0 + r_) * KSTRIDE + (c) * KC) * 2 + ps_, \
              (char*)&As[buf][0] + ldso);                                     \
      gload16((const char*)Bt + ((size_t)(n0 + r_) * KSTRIDE + (c) * KC) * 2 + ps_, \
              (char*)&Bs[buf][0] + ldso);                                     \
    }                                                                         \
  } while (0)

  facc4 acc[2][2] = {};
  STAGE(0, 0);
  if (NCH > 1) STAGE(1, 1);

  #pragma unroll
  for (int c = 0; c < NCH; ++c) {
    if (c + 1 < NCH) asm volatile("s_waitcnt vmcnt(8)\n\ts_barrier" ::: "memory");
    else             asm volatile("s_waitcnt vmcnt(0)\n\ts_barrier" ::: "memory");
    const char* ab = (const char*)&As[c & 1][0];
    const char* bb = (const char*)&Bs[c & 1][0];
    #pragma unroll
    for (int ks = 0; ks < 4; ++ks) {
      bfrag8 af[2], bfv[2];
      #pragma unroll
      for (int mf = 0; mf < 2; ++mf) {
        int rA = wr * 32 + mf * 16 + fr;
        af[mf] = *(const bfrag8*)(ab + rA * 256 + SWZ(rA, ks * 64 + fks * 16));
      }
      #pragma unroll
      for (int nf = 0; nf < 2; ++nf) {
        int rB = wc * 32 + nf * 16 + fr;
        bfv[nf] = *(const bfrag8*)(bb + rB * 256 + SWZ(rB, ks * 64 + fks * 16));
      }
      #pragma unroll
      for (int mf = 0; mf < 2; ++mf)
        #pragma unroll
        for (int nf = 0; nf < 2; ++nf)
          acc[mf][nf] = __builtin_amdgcn_mfma_f32_16x16x32_bf16(
              af[mf], bfv[nf], acc[mf][nf], 0, 0, 0);
    }
    asm volatile("s_barrier" ::: "memory");
    if (c + 2 < NCH) STAGE(c + 2, c & 1);
  }
  #undef STAGE

  #pragma unroll
  for (int mf = 0; mf < 2; ++mf) {
    #pragma unroll
    for (int nf = 0; nf < 2; ++nf) {
      int col = n0 + wc * 32 + nf * 16 + fr;
      float bb2 = 0.f;
      if (EPI == EPI_QKV)
        bb2 = col < 512 ? bias[col] : (col < 1024 ? bias2[col - 512] : bias3[col - 1024]);
      else if (EPI != EPI_PART)
        bb2 = bias[col];
      #pragma unroll
      for (int j = 0; j < 4; ++j) {
        int row = m0 + wr * 32 + mf * 16 + fks * 4 + j;
        float c = acc[mf][nf][j] + bb2;
        if (EPI == EPI_PART) {
          Cf[(size_t)kz * pstride + (size_t)row * N + col] = c;
        } else if (EPI == EPI_RESID) {
          c += resid[(size_t)row * N + col];
          Cf[(size_t)row * N + col] = c;
        } else {
          if (EPI == EPI_GELU) c = 0.5f * c * (1.0f + erff(c * 0.70710678118654752f));
          Cb[(size_t)row * N + col] = __float2bfloat16(c);
        }
      }
    }
  }
}

// ========== fused attention: scores MFMA + softmax + PV (split chains) =====
__global__ __launch_bounds__(256) void attn_f(
    const __hip_bfloat16* __restrict__ qkv,
    const __hip_bfloat16* __restrict__ tikb,
    const int* __restrict__ tm, const int* __restrict__ mask,
    const float* __restrict__ tiV, __hip_bfloat16* __restrict__ hh)
{
  const int h = blockIdx.y, b = blockIdx.z;
  const int i0 = blockIdx.x * 8;
  const int tid = threadIdx.x, wv = tid >> 6, lane = tid & 63;
  const int fr = lane & 15, fks = lane >> 4;
  __shared__ float S[8][160];
  __shared__ float Gsh[8][272];
  __shared__ float P[8][176];
  __shared__ int tmsh[8][176];

  bfrag8 aq0, aq1;
  {
    const __hip_bfloat16* qrow =
        qkv + (size_t)(b * SS + i0 + (fr < 8 ? fr : 7)) * 1536 + h * 64;
    aq0 = *(const bfrag8*)(qrow + fks * 8);
    aq1 = *(const bfrag8*)(qrow + 32 + fks * 8);
  }
  for (int tt = wv; tt < 27; tt += 4) {
    facc4 acc = {};
    if (tt < 10) {
      int j = tt * 16 + fr;
      const __hip_bfloat16* krow = qkv + (size_t)(b * SS + j) * 1536 + 512 + h * 64;
      bfrag8 b0 = *(const bfrag8*)(krow + fks * 8);
      bfrag8 b1 = *(const bfrag8*)(krow + 32 + fks * 8);
      acc = __builtin_amdgcn_mfma_f32_16x16x32_bf16(aq0, b0, acc, 0, 0, 0);
      acc = __builtin_amdgcn_mfma_f32_16x16x32_bf16(aq1, b1, acc, 0, 0, 0);
      #pragma unroll
      for (int jj = 0; jj < 4; ++jj) {
        int qr = fks * 4 + jj;
        if (qr < 8) S[qr][tt * 16 + fr] = acc[jj];
      }
    } else {
      int t0 = (tt - 10) * 16;
      int t = min(t0 + fr, NTT - 1);
      const __hip_bfloat16* trow = tikb + (size_t)t * 512 + h * 64;
      bfrag8 b0 = *(const bfrag8*)(trow + fks * 8);
      bfrag8 b1 = *(const bfrag8*)(trow + 32 + fks * 8);
      acc = __builtin_amdgcn_mfma_f32_16x16x32_bf16(aq0, b0, acc, 0, 0, 0);
      acc = __builtin_amdgcn_mfma_f32_16x16x32_bf16(aq1, b1, acc, 0, 0, 0);
      #pragma unroll
      for (int jj = 0; jj < 4; ++jj) {
        int qr = fks * 4 + jj;
        if (qr < 8) Gsh[qr][t0 + fr] = acc[jj];
      }
    }
  }
  __syncthreads();

  float rinvs[2];
  #pragma unroll
  for (int rr = 0; rr < 2; ++rr) {
    const int r = wv * 2 + rr, i = i0 + r, m = b * SS + i;
    const int* tmrow = tm + (size_t)m * SS;
    float sv[3];
    float mx = -1e30f;
    #pragma unroll
    for (int g = 0; g < 3; ++g) {
      int j = lane + g * 64;
      if (j < SS) {
        int t = tmrow[j];
        tmsh[r][j] = t;
        float s = (S[r][j] + Gsh[r][t]) * 0.125f
                + 10000.0f * (1.0f - (float)mask[b * SS + j]);
        sv[g] = s; mx = fmaxf(mx, s);
      } else sv[g] = -1e30f;
    }
    #pragma unroll
    for (int off = 1; off < 64; off <<= 1) mx = fmaxf(mx, __shfl_xor(mx, off));
    float sum = 0.f;
    #pragma unroll
    for (int g = 0; g < 3; ++g) {
      int j = lane + g * 64;
      if (j < SS) { float p = expf(sv[g] - mx); P[r][j] = p; sum += p; }
    }
    #pragma unroll
    for (int off = 1; off < 64; off <<= 1) sum += __shfl_xor(sum, off);
    rinvs[rr] = 1.0f / sum;
  }

  // PV: two independent 80-iter chains per row (halves serial FMA latency)
  const int r0 = wv * 2, r1 = r0 + 1;
  const int ii0 = i0 + r0, ii1 = i0 + r1;
  const __hip_bfloat16* vbase = qkv + (size_t)b * SS * 1536 + 1024 + h * 64 + lane;
  const float* tvbase = tiV + h * 64 + lane;
  float a0a = 0.f, a0b = 0.f, a1a = 0.f, a1b = 0.f;
  #pragma unroll 4
  for (int j = 0; j < 80; ++j) {
    float vva = __bfloat162float(vbase[(size_t)j * 1536]);
    float vvb = __bfloat162float(vbase[(size_t)(j + 80) * 1536]);
    int t0a = tmsh[r0][j], t0b = tmsh[r0][j + 80];
    int t1a = tmsh[r1][j], t1b = tmsh[r1][j + 80];
    a0a += P[r0][j]      * (vva + tvbase[(size_t)t0a * 512]);
    a0b += P[r0][j + 80] * (vvb + tvbase[(size_t)t0b * 512]);
    a1a += P[r1][j]      * (vva + tvbase[(size_t)t1a * 512]);
    a1b += P[r1][j + 80] * (vvb + tvbase[(size_t)t1b * 512]);
  }
  hh[((size_t)(b * SS) + ii0) * DD + h * 64 + lane] =
      __float2bfloat16((a0a + a0b) * rinvs[0]);
  hh[((size_t)(b * SS) + ii1) * DD + h * 64 + lane] =
      __float2bfloat16((a1a + a1b) * rinvs[1]);
}

// ---------------- launch ----------------
extern "C" void kernel_launch(void* const* d_in, const int* in_sizes, int n_in,
                              void* d_out, int out_size, void* d_ws, size_t ws_size,
                              hipStream_t stream) {
  const int*   x     = (const int*)d_in[0];
  const int*   stamp = (const int*)d_in[1];
  const int*   mask  = (const int*)d_in[2];
  const int*   tm    = (const int*)d_in[3];
  const float* tok   = (const float*)d_in[4];
  const float* month = (const float*)d_in[5];
  const float* day   = (const float*)d_in[6];
  const float* tiK   = (const float*)d_in[7];
  const float* tiV   = (const float*)d_in[8];
  const float* g0    = (const float*)d_in[9];
  const float* b0    = (const float*)d_in[10];
  const float* Wq    = (const float*)d_in[11];
  const float* bq    = (const float*)d_in[12];
  const float* Wk    = (const float*)d_in[13];
  const float* bk    = (const float*)d_in[14];
  const float* Wv    = (const float*)d_in[15];
  const float* bv    = (const float*)d_in[16];
  const float* Wo    = (const float*)d_in[17];
  const float* bo    = (const float*)d_in[18];
  const float* g1    = (const float*)d_in[19];
  const float* b1    = (const float*)d_in[20];
  const float* W1    = (const float*)d_in[21];
  const float* c1    = (const float*)d_in[22];
  const float* W2    = (const float*)d_in[23];
  const float* c2    = (const float*)d_in[24];
  const float* g2    = (const float*)d_in[25];
  const float* b2    = (const float*)d_in[26];

  float* out = (float*)d_out;
  const size_t NT = (size_t)MTOK * DD;

  char* p = (char*)d_ws;
  float* h    = (float*)p;  p += NT * 4;
  float* tbp  = (float*)p;  p += (size_t)4 * NT * 4;   // 4 K-slice partials
  __hip_bfloat16* h_bf   = (__hip_bfloat16*)p;  p += NT * 2;
  __hip_bfloat16* hh_bf  = (__hip_bfloat16*)p;  p += NT * 2;
  __hip_bfloat16* fb_bf  = (__hip_bfloat16*)p;  p += (size_t)MTOK * FFD * 2;
  __hip_bfloat16* qkv_bf = (__hip_bfloat16*)p;  p += (size_t)MTOK * 1536 * 2;
  __hip_bfloat16* tikb   = (__hip_bfloat16*)p;  p += (size_t)NTT * DD * 2;
  __hip_bfloat16* wqkv   = (__hip_bfloat16*)p;  p += (size_t)2 * 1536 * 512 * 2;
  __hip_bfloat16* wo_t   = (__hip_bfloat16*)p;  p += (size_t)2 * 512 * 512 * 2;
  __hip_bfloat16* w1_t   = (__hip_bfloat16*)p;  p += (size_t)2 * 2048 * 512 * 2;
  __hip_bfloat16* w2_t   = (__hip_bfloat16*)p;  p += (size_t)2 * 512 * 2048 * 2;

  prep_all<<<2305, 256, 0, stream>>>(Wq, Wk, Wv, Wo, W1, W2, tiK,
                                     wqkv, wo_t, w1_t, w2_t, tikb,
                                     x, stamp, tok, month, day, g0, b0, h, h_bf);

  // gemm_ck args (10): A, Bt, bias, bias2, bias3, resid, Cf, Cb, N, pstride
  for (int l = 0; l < 2; ++l) {
    gemm_ck<EPI_QKV, 512, 512><<<dim3(24, 10), 256, 0, stream>>>(
        h_bf, wqkv + (size_t)l * 1536 * 512, bq + l*DD, bk + l*DD, bv + l*DD,
        nullptr, nullptr, qkv_bf, 1536, 0);

    attn_f<<<dim3(20, 8, 4), 256, 0, stream>>>(qkv_bf, tikb, tm, mask, tiV, hh_bf);

    gemm_ck<EPI_PART, 128, 512><<<dim3(8, 10, 4), 256, 0, stream>>>(
        hh_bf, wo_t + (size_t)l * 512 * 512, nullptr, nullptr, nullptr,
        nullptr, tbp, nullptr, 512, (int)NT);
    ln_red<<<MTOK, 256, 0, stream>>>(tbp, h, bo + l*DD,
                                     g1 + l*DD, b1 + l*DD, h, h_bf);

    gemm_ck<EPI_GELU, 512, 512><<<dim3(32, 10), 256, 0, stream>>>(
        h_bf, w1_t + (size_t)l * 2048 * 512, c1 + l*FFD, nullptr, nullptr,
        nullptr, nullptr, fb_bf, 2048, 0);

    gemm_ck<EPI_PART, 512, 2048><<<dim3(8, 10, 4), 256, 0, stream>>>(
        fb_bf, w2_t + (size_t)l * 512 * 2048, nullptr, nullptr, nullptr,
        nullptr, tbp, nullptr, 512, (int)NT);
    ln_red<<<MTOK, 256, 0, stream>>>(tbp, h, c2 + l*DD,
                                     g2 + l*DD, b2 + l*DD,
                                     (l == 1) ? out : h,
                                     (l == 1) ? nullptr : h_bf);
  }
}